// Round 1
// baseline (438.669 us; speedup 1.0000x reference)
//
#include <hip/hip_runtime.h>
#include <hip/hip_bf16.h>
#include <stdint.h>

#define M_POS 0.5f
#define M_NEG 0.1f
#define LAM_NEG 1.0f

typedef __attribute__((ext_vector_type(8))) short short8;   // 8 bf16 = 4 VGPRs
typedef __attribute__((ext_vector_type(4))) float floatx4;  // MFMA accumulator

// ---------------- Kernel A: row sumsq, inv_norm, fp32 -> bf16 cast ----------------
__global__ __launch_bounds__(256) void prep_kernel(
    const float* __restrict__ cb, __hip_bfloat16* __restrict__ cb_bf,
    float* __restrict__ sq, float* __restrict__ inv_norm, int N, int d)
{
    const int row = blockIdx.x;
    const float* src = cb + (size_t)row * d;
    __hip_bfloat16* dst = cb_bf + (size_t)row * d;
    const int t = threadIdx.x;

    float s = 0.f;
    for (int c = t * 4; c < d; c += blockDim.x * 4) {
        float4 v = *(const float4*)(src + c);
        s += v.x * v.x + v.y * v.y + v.z * v.z + v.w * v.w;
        __hip_bfloat16 h[4];
        h[0] = __float2bfloat16(v.x);
        h[1] = __float2bfloat16(v.y);
        h[2] = __float2bfloat16(v.z);
        h[3] = __float2bfloat16(v.w);
        *(uint2*)(dst + c) = *(uint2*)h;   // 8-byte packed store
    }

    // block reduction (4 waves)
    for (int o = 32; o > 0; o >>= 1) s += __shfl_down(s, o, 64);
    __shared__ float wsum[4];
    if ((t & 63) == 0) wsum[t >> 6] = s;
    __syncthreads();
    if (t == 0) {
        float tot = wsum[0] + wsum[1] + wsum[2] + wsum[3];
        sq[row] = tot;
        inv_norm[row] = rsqrtf(tot);
    }
}

// ---------------- Kernel B: fused Gram GEMM (C = A * A^T) + loss epilogue ----------------
// 128x128 tile, BK=64, 4 waves of 64x64 (4x4 accs of 16x16x32 bf16 MFMA)
__global__ __launch_bounds__(256) void gram_loss_kernel(
    const __hip_bfloat16* __restrict__ A,   // N x d bf16
    const float* __restrict__ sq, const float* __restrict__ inv_norm,
    const int* __restrict__ starts, const int* __restrict__ ends,
    const int* __restrict__ max_ip,
    float* __restrict__ pos_acc, float* __restrict__ neg_acc,
    int N, int d)
{
    const int M = min(N, max_ip[0] + 1);

    __shared__ __hip_bfloat16 ldsA[128 * 64];
    __shared__ __hip_bfloat16 ldsB[128 * 64];

    const int tid  = threadIdx.x;
    const int wave = tid >> 6;
    const int lane = tid & 63;
    const int rowBase = blockIdx.y * 128;
    const int colBase = blockIdx.x * 128;
    const int wr = (wave >> 1) * 64;   // wave row offset inside tile
    const int wc = (wave & 1) * 64;    // wave col offset inside tile

    floatx4 acc[4][4];
#pragma unroll
    for (int a = 0; a < 4; ++a)
#pragma unroll
        for (int b = 0; b < 4; ++b) acc[a][b] = (floatx4){0.f, 0.f, 0.f, 0.f};

    // async staging: per wave-issue, 8 rows x 64 cols; lds dest = uniform base + lane*16B
    const int ldRow = lane >> 3;        // 0..7
    const int ldCol = (lane & 7) * 8;   // bf16 col offset, 16B per lane
    const int kTiles = d / 64;

    for (int kt = 0; kt < kTiles; ++kt) {
        __syncthreads();   // previous tile fully consumed
        const int k0 = kt * 64;
#pragma unroll
        for (int q = 0; q < 4; ++q) {
            const int r = q * 32 + wave * 8 + ldRow;
            const __hip_bfloat16* ga = A + (size_t)(rowBase + r) * d + k0 + ldCol;
            const __hip_bfloat16* gb = A + (size_t)(colBase + r) * d + k0 + ldCol;
            __builtin_amdgcn_global_load_lds(
                (const __attribute__((address_space(1))) void*)ga,
                (__attribute__((address_space(3))) void*)(ldsA + r * 64 + ldCol), 16, 0, 0);
            __builtin_amdgcn_global_load_lds(
                (const __attribute__((address_space(1))) void*)gb,
                (__attribute__((address_space(3))) void*)(ldsB + r * 64 + ldCol), 16, 0, 0);
        }
        __syncthreads();   // compiler drains vmcnt before s_barrier

        const int rl = lane & 15;
        const int kq = (lane >> 4) * 8;
#pragma unroll
        for (int ko = 0; ko < 2; ++ko) {
            const int kk = ko * 32 + kq;
            short8 af[4], bf[4];
#pragma unroll
            for (int t4 = 0; t4 < 4; ++t4) {
                af[t4] = *(const short8*)(ldsA + (wr + t4 * 16 + rl) * 64 + kk);
                bf[t4] = *(const short8*)(ldsB + (wc + t4 * 16 + rl) * 64 + kk);
            }
#pragma unroll
            for (int rt = 0; rt < 4; ++rt)
#pragma unroll
                for (int ct = 0; ct < 4; ++ct)
                    acc[rt][ct] = __builtin_amdgcn_mfma_f32_16x16x32_bf16(
                        af[rt], bf[ct], acc[rt][ct], 0, 0, 0);
        }
    }

    // ---- epilogue: loss terms + per-row reduction ----
    const int rl = lane & 15;
    const int q  = lane >> 4;

    int   jn[4];
    float jsq[4], jinv[4];
#pragma unroll
    for (int ct = 0; ct < 4; ++ct) {
        const int j = colBase + wc + ct * 16 + rl;
        jn[ct]  = j;
        jsq[ct] = sq[j];
        jinv[ct] = inv_norm[j];
    }

#pragma unroll
    for (int rt = 0; rt < 4; ++rt) {
        const int ibase = rowBase + wr + rt * 16 + q * 4;
#pragma unroll
        for (int reg = 0; reg < 4; ++reg) {
            const int i = ibase + reg;
            const bool rowValid = (i < M);
            const int ns = rowValid ? starts[i] : 0;
            const int ne = rowValid ? ends[i]   : -1;
            const float isq  = sq[i];
            const float iinv = inv_norm[i];
            float posp = 0.f, negp = 0.f;
#pragma unroll
            for (int ct = 0; ct < 4; ++ct) {
                const float dot = acc[rt][ct][reg];
                const int j = jn[ct];
                float cosv = dot * iinv * jinv[ct];
                cosv = fminf(fmaxf(cosv, -1.f), 1.f);
                float tn = fmaxf(fabsf(cosv) - M_NEG, 0.f);
                const float nterm = tn * tn;
                const float d2 = fmaxf(isq + jsq[ct] - 2.f * dot, 0.f);
                float tp = fmaxf(sqrtf(d2) - M_POS, 0.f);
                const float pterm = tp * tp;
                const bool in_range = (j >= ns) && (j <= ne);
                const bool diag = (j == i);
                if (in_range && !diag) posp += pterm;
                if (!in_range || diag) negp += nterm;
            }
            // sum over the 16 column-lanes of this row
#pragma unroll
            for (int m = 1; m < 16; m <<= 1) {
                posp += __shfl_xor(posp, m, 64);
                negp += __shfl_xor(negp, m, 64);
            }
            if (rowValid && rl == 0) {
                atomicAdd(&pos_acc[i], posp);
                atomicAdd(&neg_acc[i], negp);
            }
        }
    }
}

// ---------------- Kernel C: per-row normalize + global mean ----------------
__global__ __launch_bounds__(1024) void finalize_kernel(
    const float* __restrict__ pos_acc, const float* __restrict__ neg_acc,
    const int* __restrict__ starts, const int* __restrict__ ends,
    const int* __restrict__ max_ip, int N, float* __restrict__ out)
{
    const int M = min(N, max_ip[0] + 1);
    const int t = threadIdx.x;
    float total = 0.f;
    int cnt = 0;
    for (int i = t; i < M; i += blockDim.x) {
        const int ns = starts[i], ne = ends[i];
        const int lo = max(ns, 0), hi = min(ne, N - 1);
        const int inr = max(hi - lo + 1, 0);
        const bool diag = (i >= ns) && (i <= ne);
        const int pos_cnt = inr - (diag ? 1 : 0);
        const int neg_cnt = N - inr + (diag ? 1 : 0);
        if (pos_cnt > 0 && neg_cnt > 0) {
            total += pos_acc[i] / (float)max(pos_cnt, 1)
                   + LAM_NEG * neg_acc[i] / (float)max(neg_cnt, 1);
            cnt++;
        }
    }
    for (int o = 32; o > 0; o >>= 1) {
        total += __shfl_down(total, o, 64);
        cnt   += __shfl_down(cnt, o, 64);
    }
    __shared__ float ts[16];
    __shared__ int   cs[16];
    const int w = t >> 6;
    if ((t & 63) == 0) { ts[w] = total; cs[w] = cnt; }
    __syncthreads();
    if (t == 0) {
        float T = 0.f; int C = 0;
        const int nw = blockDim.x >> 6;
        for (int i = 0; i < nw; ++i) { T += ts[i]; C += cs[i]; }
        out[0] = (C > 0) ? T / (float)C : 0.f;
    }
}

extern "C" void kernel_launch(void* const* d_in, const int* in_sizes, int n_in,
                              void* d_out, int out_size, void* d_ws, size_t ws_size,
                              hipStream_t stream) {
    const float* cb     = (const float*)d_in[0];
    const int*   starts = (const int*)d_in[1];
    const int*   ends   = (const int*)d_in[2];
    const int*   max_ip = (const int*)d_in[3];
    float* out = (float*)d_out;

    const int N = in_sizes[1];
    const int d = in_sizes[0] / N;

    char* ws = (char*)d_ws;
    __hip_bfloat16* cb_bf = (__hip_bfloat16*)ws;
    size_t off = ((size_t)N * d * sizeof(__hip_bfloat16) + 255) & ~(size_t)255;
    float* sq       = (float*)(ws + off); off += (size_t)N * 4;
    float* inv_norm = (float*)(ws + off); off += (size_t)N * 4;
    float* pos_acc  = (float*)(ws + off); off += (size_t)N * 4;
    float* neg_acc  = (float*)(ws + off); off += (size_t)N * 4;

    // zero the atomic accumulators (pos_acc, neg_acc are contiguous)
    hipMemsetAsync(pos_acc, 0, (size_t)2 * N * sizeof(float), stream);

    prep_kernel<<<N, 256, 0, stream>>>(cb, cb_bf, sq, inv_norm, N, d);

    dim3 grid(N / 128, N / 128);
    gram_loss_kernel<<<grid, 256, 0, stream>>>(cb_bf, sq, inv_norm, starts, ends,
                                               max_ip, pos_acc, neg_acc, N, d);

    finalize_kernel<<<1, 1024, 0, stream>>>(pos_acc, neg_acc, starts, ends, max_ip, N, out);
}

// Round 2
// 263.885 us; speedup vs baseline: 1.6624x; 1.6624x over previous
//
#include <hip/hip_runtime.h>
#include <hip/hip_bf16.h>
#include <stdint.h>

#define M_POS 0.5f
#define M_NEG 0.1f
#define LAM_NEG 1.0f

typedef __attribute__((ext_vector_type(8))) short short8;   // 8 bf16 = 4 VGPRs
typedef __attribute__((ext_vector_type(4))) float floatx4;  // MFMA accumulator

// ---------------- Kernel A: row sumsq, inv_norm, fp32 -> bf16 cast ----------------
// One wave per row (4 rows/block): wave-level reduction only, no barriers.
__global__ __launch_bounds__(256) void prep_kernel(
    const float* __restrict__ cb, __hip_bfloat16* __restrict__ cb_bf,
    float* __restrict__ sq, float* __restrict__ inv_norm, int N, int d)
{
    const int wave = threadIdx.x >> 6;
    const int lane = threadIdx.x & 63;
    const int row = blockIdx.x * 4 + wave;
    if (row >= N) return;
    const float* src = cb + (size_t)row * d;
    __hip_bfloat16* dst = cb_bf + (size_t)row * d;

    float s = 0.f;
    for (int c = lane * 4; c < d; c += 256) {
        float4 v = *(const float4*)(src + c);
        s += v.x * v.x + v.y * v.y + v.z * v.z + v.w * v.w;
        __hip_bfloat16 h[4];
        h[0] = __float2bfloat16(v.x);
        h[1] = __float2bfloat16(v.y);
        h[2] = __float2bfloat16(v.z);
        h[3] = __float2bfloat16(v.w);
        *(uint2*)(dst + c) = *(uint2*)h;
    }
    for (int o = 32; o > 0; o >>= 1) s += __shfl_down(s, o, 64);
    if (lane == 0) {
        sq[row] = s;
        inv_norm[row] = rsqrtf(s);
    }
}

// ---------------- Kernel B: fused symmetric Gram GEMM + loss epilogue ----------------
// Upper-triangular 128x128 tiles only (by <= bx). Off-diagonal tiles contribute each
// element (i,j) to BOTH row i (mask_i) and row j (mask_j) — exact since d2/cos are
// symmetric. LDS chunks XOR-swizzled (chunk' = chunk ^ (row&7)) so fragment
// ds_read_b128 hits all 32 banks (global_load_lds dest stays lane-linear; only the
// per-lane global source is permuted within the same 128B segment).
__global__ __launch_bounds__(256) void gram_loss_kernel(
    const __hip_bfloat16* __restrict__ A,   // N x d bf16
    const float* __restrict__ sq, const float* __restrict__ inv_norm,
    const int* __restrict__ starts, const int* __restrict__ ends,
    const int* __restrict__ max_ip,
    float* __restrict__ pos_acc, float* __restrict__ neg_acc,
    int N, int d)
{
    const int M = min(N, max_ip[0] + 1);

    // triangular decode: blockIdx.x -> (by, bx), by <= bx
    const int t = blockIdx.x;
    int bx = (int)((sqrtf(8.f * (float)t + 1.f) - 1.f) * 0.5f);
    while ((bx + 1) * (bx + 2) / 2 <= t) bx++;
    while (bx * (bx + 1) / 2 > t) bx--;
    const int by = t - bx * (bx + 1) / 2;

    const int rowBase = by * 128;
    const int colBase = bx * 128;
    const bool isDiag = (by == bx);

    __shared__ __hip_bfloat16 ldsA[128 * 64];
    __shared__ __hip_bfloat16 ldsB[128 * 64];

    const int tid  = threadIdx.x;
    const int wave = tid >> 6;
    const int lane = tid & 63;
    const int wr = (wave >> 1) * 64;   // wave row offset inside tile
    const int wc = (wave & 1) * 64;    // wave col offset inside tile

    floatx4 acc[4][4];
#pragma unroll
    for (int a = 0; a < 4; ++a)
#pragma unroll
        for (int b = 0; b < 4; ++b) acc[a][b] = (floatx4){0.f, 0.f, 0.f, 0.f};

    // staging: dest = uniform base + lane*16B (required); source chunk XOR-swizzled
    const int ldRow = lane >> 3;                    // 0..7
    const int dstCol = (lane & 7) * 8;              // bf16 elements
    const int srcCol = ((lane ^ ldRow) & 7) * 8;    // chunk ^ (row&7)
    const int kTiles = d / 64;

    for (int kt = 0; kt < kTiles; ++kt) {
        __syncthreads();
        const int k0 = kt * 64;
#pragma unroll
        for (int q = 0; q < 4; ++q) {
            const int r = q * 32 + wave * 8 + ldRow;
            const __hip_bfloat16* ga = A + (size_t)(rowBase + r) * d + k0 + srcCol;
            const __hip_bfloat16* gb = A + (size_t)(colBase + r) * d + k0 + srcCol;
            __builtin_amdgcn_global_load_lds(
                (const __attribute__((address_space(1))) void*)ga,
                (__attribute__((address_space(3))) void*)(ldsA + r * 64 + dstCol), 16, 0, 0);
            __builtin_amdgcn_global_load_lds(
                (const __attribute__((address_space(1))) void*)gb,
                (__attribute__((address_space(3))) void*)(ldsB + r * 64 + dstCol), 16, 0, 0);
        }
        __syncthreads();

        const int rl = lane & 15;
        const int g  = lane >> 4;   // 0..3
#pragma unroll
        for (int ko = 0; ko < 2; ++ko) {
            const int kc = ko * 4 + g;
            short8 af[4], bf[4];
#pragma unroll
            for (int t4 = 0; t4 < 4; ++t4) {
                const int ra = wr + t4 * 16 + rl;
                const int rb = wc + t4 * 16 + rl;
                af[t4] = *(const short8*)(ldsA + ra * 64 + ((kc ^ (rl & 7)) * 8));
                bf[t4] = *(const short8*)(ldsB + rb * 64 + ((kc ^ (rl & 7)) * 8));
            }
#pragma unroll
            for (int rt = 0; rt < 4; ++rt)
#pragma unroll
                for (int ct = 0; ct < 4; ++ct)
                    acc[rt][ct] = __builtin_amdgcn_mfma_f32_16x16x32_bf16(
                        af[rt], bf[ct], acc[rt][ct], 0, 0, 0);
        }
    }

    // ---- epilogue ----
    const int rl = lane & 15;
    const int q  = lane >> 4;

    int   jn[4], jns[4], jne[4];
    float jsq[4], jinv[4];
#pragma unroll
    for (int ct = 0; ct < 4; ++ct) {
        const int j = colBase + wc + ct * 16 + rl;
        jn[ct]  = j;
        jsq[ct] = sq[j];
        jinv[ct] = inv_norm[j];
        const bool jv = (j < M);
        jns[ct] = jv ? starts[j] : 0;
        jne[ct] = jv ? ends[j]   : -1;
    }

    float posc[4] = {0.f, 0.f, 0.f, 0.f};
    float negc[4] = {0.f, 0.f, 0.f, 0.f};

#pragma unroll
    for (int rt = 0; rt < 4; ++rt) {
        const int ibase = rowBase + wr + rt * 16 + q * 4;
#pragma unroll
        for (int reg = 0; reg < 4; ++reg) {
            const int i = ibase + reg;
            const bool rowValid = (i < M);
            const int ns = rowValid ? starts[i] : 0;
            const int ne = rowValid ? ends[i]   : -1;
            const float isq  = sq[i];
            const float iinv = inv_norm[i];
            float posp = 0.f, negp = 0.f;
#pragma unroll
            for (int ct = 0; ct < 4; ++ct) {
                const float dot = acc[rt][ct][reg];
                const int j = jn[ct];
                float cosv = dot * iinv * jinv[ct];
                cosv = fminf(fmaxf(cosv, -1.f), 1.f);
                float tn = fmaxf(fabsf(cosv) - M_NEG, 0.f);
                const float nterm = tn * tn;
                const float d2 = fmaxf(isq + jsq[ct] - 2.f * dot, 0.f);
                float tp = fmaxf(sqrtf(d2) - M_POS, 0.f);
                const float pterm = tp * tp;
                const bool dg = (j == i);
                // row-i contribution (mask of row i)
                if (rowValid) {
                    const bool in_r = (j >= ns) && (j <= ne);
                    if (in_r && !dg) posp += pterm;
                    if (!in_r || dg) negp += nterm;
                }
                // row-j contribution (mask of row j) — off-diagonal tiles only
                if (!isDiag && (j < M)) {
                    const bool in_c = (i >= jns[ct]) && (i <= jne[ct]);
                    if (in_c && !dg) posc[ct] += pterm;
                    if (!in_c || dg) negc[ct] += nterm;
                }
            }
            // reduce over the 16 column-lanes of this row
#pragma unroll
            for (int m = 1; m < 16; m <<= 1) {
                posp += __shfl_xor(posp, m, 64);
                negp += __shfl_xor(negp, m, 64);
            }
            if (rowValid && rl == 0) {
                atomicAdd(&pos_acc[i], posp);
                atomicAdd(&neg_acc[i], negp);
            }
        }
    }

    if (!isDiag) {
        // reduce column partials over the 4 q-groups, then one atomic per j
#pragma unroll
        for (int ct = 0; ct < 4; ++ct) {
            posc[ct] += __shfl_xor(posc[ct], 16, 64);
            posc[ct] += __shfl_xor(posc[ct], 32, 64);
            negc[ct] += __shfl_xor(negc[ct], 16, 64);
            negc[ct] += __shfl_xor(negc[ct], 32, 64);
        }
        if (q == 0) {
#pragma unroll
            for (int ct = 0; ct < 4; ++ct) {
                if (jn[ct] < M) {
                    atomicAdd(&pos_acc[jn[ct]], posc[ct]);
                    atomicAdd(&neg_acc[jn[ct]], negc[ct]);
                }
            }
        }
    }
}

// ---------------- Kernel C: per-row normalize + global mean ----------------
__global__ __launch_bounds__(1024) void finalize_kernel(
    const float* __restrict__ pos_acc, const float* __restrict__ neg_acc,
    const int* __restrict__ starts, const int* __restrict__ ends,
    const int* __restrict__ max_ip, int N, float* __restrict__ out)
{
    const int M = min(N, max_ip[0] + 1);
    const int t = threadIdx.x;
    float total = 0.f;
    int cnt = 0;
    for (int i = t; i < M; i += blockDim.x) {
        const int ns = starts[i], ne = ends[i];
        const int lo = max(ns, 0), hi = min(ne, N - 1);
        const int inr = max(hi - lo + 1, 0);
        const bool diag = (i >= ns) && (i <= ne);
        const int pos_cnt = inr - (diag ? 1 : 0);
        const int neg_cnt = N - inr + (diag ? 1 : 0);
        if (pos_cnt > 0 && neg_cnt > 0) {
            total += pos_acc[i] / (float)max(pos_cnt, 1)
                   + LAM_NEG * neg_acc[i] / (float)max(neg_cnt, 1);
            cnt++;
        }
    }
    for (int o = 32; o > 0; o >>= 1) {
        total += __shfl_down(total, o, 64);
        cnt   += __shfl_down(cnt, o, 64);
    }
    __shared__ float ts[16];
    __shared__ int   cs[16];
    const int w = t >> 6;
    if ((t & 63) == 0) { ts[w] = total; cs[w] = cnt; }
    __syncthreads();
    if (t == 0) {
        float T = 0.f; int C = 0;
        const int nw = blockDim.x >> 6;
        for (int i = 0; i < nw; ++i) { T += ts[i]; C += cs[i]; }
        out[0] = (C > 0) ? T / (float)C : 0.f;
    }
}

extern "C" void kernel_launch(void* const* d_in, const int* in_sizes, int n_in,
                              void* d_out, int out_size, void* d_ws, size_t ws_size,
                              hipStream_t stream) {
    const float* cb     = (const float*)d_in[0];
    const int*   starts = (const int*)d_in[1];
    const int*   ends   = (const int*)d_in[2];
    const int*   max_ip = (const int*)d_in[3];
    float* out = (float*)d_out;

    const int N = in_sizes[1];
    const int d = in_sizes[0] / N;

    char* ws = (char*)d_ws;
    __hip_bfloat16* cb_bf = (__hip_bfloat16*)ws;
    size_t off = ((size_t)N * d * sizeof(__hip_bfloat16) + 255) & ~(size_t)255;
    float* sq       = (float*)(ws + off); off += (size_t)N * 4;
    float* inv_norm = (float*)(ws + off); off += (size_t)N * 4;
    float* pos_acc  = (float*)(ws + off); off += (size_t)N * 4;
    float* neg_acc  = (float*)(ws + off); off += (size_t)N * 4;

    hipMemsetAsync(pos_acc, 0, (size_t)2 * N * sizeof(float), stream);

    prep_kernel<<<(N + 3) / 4, 256, 0, stream>>>(cb, cb_bf, sq, inv_norm, N, d);

    const int nb = N / 128;
    const int nBlocks = nb * (nb + 1) / 2;   // upper-triangular tiles
    gram_loss_kernel<<<nBlocks, 256, 0, stream>>>(cb_bf, sq, inv_norm, starts, ends,
                                                  max_ip, pos_acc, neg_acc, N, d);

    finalize_kernel<<<1, 1024, 0, stream>>>(pos_acc, neg_acc, starts, ends, max_ip, N, out);
}